// Round 9
// baseline (1754.071 us; speedup 1.0000x reference)
//
#include <hip/hip_runtime.h>
#include <hip/hip_bf16.h>

typedef unsigned short u16;
typedef unsigned long long u64;
typedef __attribute__((ext_vector_type(8))) short short8;
typedef __attribute__((ext_vector_type(4))) float floatx4;

__device__ __forceinline__ u16 f2bf(float f) {
    union { float f; unsigned u; } v; v.f = f;
    unsigned r = v.u + 0x7FFF + ((v.u >> 16) & 1);
    return (u16)(r >> 16);
}

// packed f32x2 -> bf16x2 (low = a)
__device__ __forceinline__ unsigned pk2bf(float a, float b) {
#if defined(__has_builtin)
#if __has_builtin(__builtin_amdgcn_cvt_pk_bf16_f32)
    auto v = __builtin_amdgcn_cvt_pk_bf16_f32(a, b);
    unsigned u; __builtin_memcpy(&u, &v, 4); return u;
#else
    return (unsigned)f2bf(a) | ((unsigned)f2bf(b) << 16);
#endif
#else
    return (unsigned)f2bf(a) | ((unsigned)f2bf(b) << 16);
#endif
}

// ---------------------------------------------------------------------------
// Wstack fragment builder (validated rounds 1-8).
// element (k,n) at: (k>>5)*16384 + (n>>4)*512 + ((k>>3)&3)*128 + (n&15)*8 + (k&7)
__global__ void k_wstack2(const float* __restrict__ basis, const float* __restrict__ comb,
                          const float* __restrict__ selfW, u16* __restrict__ wf) {
    int bi = blockIdx.x, t = threadIdx.x;
    int kr = t >> 7;             // 0..1
    int nb = (t & 127) * 4;      // n base
    for (int it = 0; it < 4; ++it) {
        int k = bi * 8 + it * 2 + kr;
        float v0, v1, v2, v3;
        if (k < 6144) {
            int r = k >> 9, h = k & 511;
            v0 = v1 = v2 = v3 = 0.f;
            for (int q = 0; q < 6; ++q) {
                float c = comb[r * 6 + q];
                const float4 bz = *(const float4*)(basis + ((size_t)(q * 512 + h)) * 512 + nb);
                v0 += c * bz.x; v1 += c * bz.y; v2 += c * bz.z; v3 += c * bz.w;
            }
        } else {
            int kk = k - 6144;
            v0 = selfW[(size_t)(nb + 0) * 512 + kk];
            v1 = selfW[(size_t)(nb + 1) * 512 + kk];
            v2 = selfW[(size_t)(nb + 2) * 512 + kk];
            v3 = selfW[(size_t)(nb + 3) * 512 + kk];
        }
        float vv[4] = {v0, v1, v2, v3};
        for (int i = 0; i < 4; ++i) {
            int n = nb + i;
            wf[(size_t)(k >> 5) * 16384 + (n >> 4) * 512 + ((k >> 3) & 3) * 128 + (n & 15) * 8 + (k & 7)] = f2bf(vv[i]);
        }
    }
}

// ---------------------------------------------------------------------------
// Bit-packed adjacency (validated round 6): bA/bB[b][12][64] u64 masks.
__global__ void k_adjbits(const int* __restrict__ A, u64* __restrict__ bA, u64* __restrict__ bB) {
    int bi = blockIdx.x;          // b*12 + r
    int b = bi / 12, r = bi % 12;
    const int* Ab = A + (size_t)(b * 13 + (r + 1)) * 62 * 62;
    __shared__ int tile[62 * 62];
    for (int i = threadIdx.x; i < 3844; i += 256) tile[i] = Ab[i];
    __syncthreads();
    int n = threadIdx.x;
    if (n < 64) {
        u64 mA = 0, mB = 0;
        if (n < 62)
            for (int m = 0; m < 62; ++m)
                if (tile[n * 62 + m]) mA |= 1ull << m;
        if (n < 63) {
            int oi = (n == 62) ? 63 : n;
            for (int m = 0; m < 63; ++m) {
                int oj = (m == 62) ? 63 : m;
                int val = (oi < 62 && oj < 62) ? (tile[oi * 62 + oj] ? 1 : 0) : 0;
                int lo = (oi < oj) ? oi : oj, hi = (oi < oj) ? oj : oi;
                if (hi == lo + 2) {
                    int p = (lo >> 1) & 1;
                    int chp = ((lo & 1) == 0) ? (p ? 12 : 11) : (p ? 11 : 12);
                    if (r + 1 == chp) val = 1;
                }
                if (val) mB |= 1ull << m;
            }
        }
        bA[(size_t)bi * 64 + n] = mA;
        bB[(size_t)bi * 64 + n] = mB;
    }
}

// ---------------------------------------------------------------------------
// initial embedding -> mi1 rows 60..63 ; mi2 rows 62,63
__global__ void k_prep(const int* __restrict__ player,
                       const float* __restrict__ pAx, const float* __restrict__ pAy,
                       const float* __restrict__ pBx, const float* __restrict__ pBy,
                       const float* __restrict__ emb, const float* __restrict__ cW,
                       const float* __restrict__ cb, const float* __restrict__ inW,
                       const float* __restrict__ inb,
                       u16* __restrict__ mi1, u16* __restrict__ mi2) {
    int b = blockIdx.x, t = threadIdx.x;
    __shared__ float feat[2][64];
    if (t < 64) {
        int j = t >> 5, d = t & 31;
        float X = j ? pBx[b] : pAx[b];
        float Y = j ? pBy[b] : pAy[b];
        feat[j][d] = fmaxf(cW[d * 2] * X + cW[d * 2 + 1] * Y + cb[d], 0.f);
        feat[j][32 + d] = emb[player[b * 2 + j] * 32 + d];
    }
    __syncthreads();
    for (int h = t; h < 512; h += 256) {
        float a0 = inb[h], a1 = inb[h];
        const float* wrow = inW + h * 64;
        #pragma unroll
        for (int d = 0; d < 64; ++d) {
            float wv = wrow[d];
            a0 += wv * feat[0][d];
            a1 += wv * feat[1][d];
        }
        u16 v0 = f2bf(a0), v1 = f2bf(a1);
        size_t base = (size_t)b * 64 * 512;
        mi1[base + 60 * 512 + h] = v0;
        mi1[base + 61 * 512 + h] = v1;
        mi1[base + 62 * 512 + h] = 0;
        mi1[base + 63 * 512 + h] = 0;
        mi2[base + 62 * 512 + h] = v1;
        mi2[base + 63 * 512 + h] = 0;
    }
}

// enc f32 -> mi1 rows 0..59 ; mi2 rows 0..57
__global__ void k_cast(const float* __restrict__ enc, u16* __restrict__ mi1, u16* __restrict__ mi2) {
    long long e = ((long long)blockIdx.x * 256 + threadIdx.x) * 8;
    if (e >= 256LL * 60 * 512) return;
    int b = (int)(e / (60 * 512));
    int rm = (int)(e % (60 * 512));
    int n = rm / 512, h = rm % 512;
    for (int i = 0; i < 8; ++i) {
        u16 v = f2bf(enc[e + i]);
        mi1[((size_t)b * 64 + n) * 512 + h + i] = v;
        if (n < 58) mi2[((size_t)b * 64 + n) * 512 + h + i] = v;
    }
}

// ---------------------------------------------------------------------------
// Fused RGCN layer, v6. Block = (1 batch, 64-col tile ct), 256 thr = 4 waves.
// Wave w = K-quarter. Z computed in two col-halves (az 32 acc); zs XOR-swizzled
// (bank-conflict-free); adj expanded to LDS once per r, agg B-frags via
// ds_read_b128. Target 3 blocks/CU.
__global__ __launch_bounds__(256, 3)
void k_fused(const u16* __restrict__ x, const u64* __restrict__ bits,
             const u16* __restrict__ wf, int mode,
             u16* __restrict__ o16, float* __restrict__ o32) {
    int ct = blockIdx.x & 7, b = blockIdx.x >> 3;
    int t = threadIdx.x, lane = t & 63, w = t >> 6;
    int l15 = lane & 15, lq = lane >> 4;
    int sA = (l15 & 3) << 3;                 // zs swizzle (col&3 == l15&3)

    __shared__ __align__(16) u16 zs[64 * 264];   // [col][m'^swz]
    __shared__ __align__(16) u16 adjs[64 * 72];  // adj[n][m]

    // x fragments: all 64 rows, K-quarter w (one-time load)
    short8 xf[16];
    {
        const u16* xw = x + (size_t)b * 64 * 512 + w * 128 + lq * 8;
        #pragma unroll
        for (int mt = 0; mt < 4; ++mt)
            #pragma unroll
            for (int ks = 0; ks < 4; ++ks)
                xf[mt * 4 + ks] = *(const short8*)(xw + (mt * 16 + l15) * 512 + ks * 32);
    }

    const u16* wbase = wf + (size_t)(ct * 4) * 512 + (size_t)lane * 8;
    const u64* bitb = bits + (size_t)b * 12 * 64;
    int an = t >> 2, am0 = (t & 3) * 16;     // adjs build assignment

    floatx4 ay[4];
    #pragma unroll
    for (int i = 0; i < 4; ++i) ay[i] = (floatx4)(0.f);

    for (int r = 0; r < 13; ++r) {
        u64 msk = (r < 12) ? bitb[r * 64 + an] : (1ull << an);
        const u16* wr = wbase + (size_t)(r * 16 + w * 4) * 16384;

        // ---- Z col-half 0 (cols ct*64 + 0..31)
        floatx4 az[8];                       // [mt*2+i]
        short8 wv[8];                        // [ks*2+i]
        #pragma unroll
        for (int i = 0; i < 8; ++i) az[i] = (floatx4)(0.f);
        #pragma unroll
        for (int ks = 0; ks < 4; ++ks)
            #pragma unroll
            for (int i = 0; i < 2; ++i)
                wv[ks * 2 + i] = *(const short8*)(wr + (size_t)ks * 16384 + i * 512);
        #pragma unroll
        for (int ks = 0; ks < 4; ++ks)
            #pragma unroll
            for (int mt = 0; mt < 4; ++mt)
                #pragma unroll
                for (int i = 0; i < 2; ++i)
                    az[mt * 2 + i] = __builtin_amdgcn_mfma_f32_16x16x32_bf16(xf[mt * 4 + ks], wv[ks * 2 + i], az[mt * 2 + i], 0, 0, 0);

        __syncthreads();   // prior agg's zs/adjs reads complete

        // write half 0: col = i*16+l15, m = w*64+mt*16+lq*4, swizzled
        #pragma unroll
        for (int mt = 0; mt < 4; ++mt)
            #pragma unroll
            for (int i = 0; i < 2; ++i) {
                uint2 pk;
                pk.x = pk2bf(az[mt * 2 + i][0], az[mt * 2 + i][1]);
                pk.y = pk2bf(az[mt * 2 + i][2], az[mt * 2 + i][3]);
                *(uint2*)&zs[(i * 16 + l15) * 264 + ((w * 64 + mt * 16 + lq * 4) ^ sA)] = pk;
            }

        // ---- Z col-half 1 (cols ct*64 + 32..63)
        #pragma unroll
        for (int i = 0; i < 8; ++i) az[i] = (floatx4)(0.f);
        #pragma unroll
        for (int ks = 0; ks < 4; ++ks)
            #pragma unroll
            for (int i = 0; i < 2; ++i)
                wv[ks * 2 + i] = *(const short8*)(wr + (size_t)ks * 16384 + (2 + i) * 512);
        #pragma unroll
        for (int ks = 0; ks < 4; ++ks)
            #pragma unroll
            for (int mt = 0; mt < 4; ++mt)
                #pragma unroll
                for (int i = 0; i < 2; ++i)
                    az[mt * 2 + i] = __builtin_amdgcn_mfma_f32_16x16x32_bf16(xf[mt * 4 + ks], wv[ks * 2 + i], az[mt * 2 + i], 0, 0, 0);
        #pragma unroll
        for (int mt = 0; mt < 4; ++mt)
            #pragma unroll
            for (int i = 0; i < 2; ++i) {
                uint2 pk;
                pk.x = pk2bf(az[mt * 2 + i][0], az[mt * 2 + i][1]);
                pk.y = pk2bf(az[mt * 2 + i][2], az[mt * 2 + i][3]);
                *(uint2*)&zs[((2 + i) * 16 + l15) * 264 + ((w * 64 + mt * 16 + lq * 4) ^ sA)] = pk;
            }

        // ---- build adjs[n][m] from bitmask (each thread: row an, cols am0..+16)
        {
            short8 e0, e1;
            #pragma unroll
            for (int j = 0; j < 8; ++j) {
                e0[j] = (short)(((msk >> (am0 + j)) & 1) ? 0x3F80 : 0);
                e1[j] = (short)(((msk >> (am0 + 8 + j)) & 1) ? 0x3F80 : 0);
            }
            *(short8*)&adjs[an * 72 + am0] = e0;
            *(short8*)&adjs[an * 72 + am0 + 8] = e1;
        }

        __syncthreads();   // zs + adjs visible

        // ---- agg: ay^T += Z^T @ adj^T ; A from zs (own col-band w), B from adjs
        if (mode == 0) {
            #pragma unroll
            for (int k2 = 0; k2 < 8; ++k2) {
                short8 af = *(const short8*)&zs[(w * 16 + l15) * 264 + ((k2 * 32 + lq * 8) ^ sA)];
                #pragma unroll
                for (int i = 0; i < 4; ++i) {
                    short8 bf = *(const short8*)&adjs[(i * 16 + l15) * 72 + (k2 & 1) * 32 + lq * 8];
                    ay[i] = __builtin_amdgcn_mfma_f32_16x16x32_bf16(af, bf, ay[i], 0, 0, 0);
                }
            }
        } else {
            #pragma unroll
            for (int k2 = 0; k2 < 8; ++k2) {
                short8 af = *(const short8*)&zs[(w * 16 + l15) * 264 + ((k2 * 32 + lq * 8) ^ sA)];
                short8 bf = *(const short8*)&adjs[(48 + l15) * 72 + (k2 & 1) * 32 + lq * 8];
                ay[3] = __builtin_amdgcn_mfma_f32_16x16x32_bf16(af, bf, ay[3], 0, 0, 0);
            }
        }
    }

    // ---- epilogue: lane holds y[row = i*16+l15][col = ct*64 + w*16 + lq*4 + rr]
    int colb = ct * 64 + w * 16 + lq * 4;
    #pragma unroll
    for (int i = 0; i < 4; ++i) {
        int row = i * 16 + l15;
        if (mode == 0) {
            uint2 pk;
            pk.x = pk2bf(fmaxf(ay[i][0], 0.f), fmaxf(ay[i][1], 0.f));
            pk.y = pk2bf(fmaxf(ay[i][2], 0.f), fmaxf(ay[i][3], 0.f));
            *(uint2*)(o16 + ((size_t)b * 64 + row) * 512 + colb) = pk;
        } else if (mode == 1) {
            if (i == 3 && row >= 58 && row <= 61) {
                uint2 pk;
                pk.x = pk2bf(1.f / (1.f + __expf(-ay[3][0])), 1.f / (1.f + __expf(-ay[3][1])));
                pk.y = pk2bf(1.f / (1.f + __expf(-ay[3][2])), 1.f / (1.f + __expf(-ay[3][3])));
                *(uint2*)(o16 + ((size_t)b * 64 + row) * 512 + colb) = pk;
            }
        } else {
            if (i == 3 && (row == 60 || row == 62)) {
                float4 pv;
                pv.x = 1.f / (1.f + __expf(-ay[3][0]));
                pv.y = 1.f / (1.f + __expf(-ay[3][1]));
                pv.z = 1.f / (1.f + __expf(-ay[3][2]));
                pv.w = 1.f / (1.f + __expf(-ay[3][3]));
                int slot = (row == 60) ? (b * 2) : (b * 2 + 1);
                *(float4*)(o32 + (size_t)slot * 512 + colb) = pv;
            }
        }
    }
}

// logits = [black|white] @ type_W^T + type_b
__global__ void k_final(const float* __restrict__ t2, const float* __restrict__ tW,
                        const float* __restrict__ tb, float* __restrict__ outp) {
    int b = blockIdx.x, l = threadIdx.x;   // 64 threads
    float a[11];
    #pragma unroll
    for (int j = 0; j < 11; ++j) a[j] = 0.f;
    for (int it = 0; it < 16; ++it) {
        int h = it * 64 + l;
        float c = (h < 512) ? t2[(b * 2 + 1) * 512 + h] : t2[(b * 2 + 0) * 512 + (h - 512)];
        #pragma unroll
        for (int j = 0; j < 11; ++j) a[j] += c * tW[j * 1024 + h];
    }
    #pragma unroll
    for (int j = 0; j < 11; ++j) {
        float v = a[j];
        for (int off = 32; off > 0; off >>= 1) v += __shfl_down(v, off, 64);
        if (l == 0) outp[b * 11 + j] = v + tb[j];
    }
}

// ---------------------------------------------------------------------------
extern "C" void kernel_launch(void* const* d_in, const int* in_sizes, int n_in,
                              void* d_out, int out_size, void* d_ws, size_t ws_size,
                              hipStream_t stream) {
    const int*   player = (const int*)d_in[0];
    const float* enc    = (const float*)d_in[2];
    const int*   adjm   = (const int*)d_in[3];
    const float* pAx    = (const float*)d_in[4];
    const float* pAy    = (const float*)d_in[5];
    const float* pBx    = (const float*)d_in[6];
    const float* pBy    = (const float*)d_in[7];
    const float* emb    = (const float*)d_in[8];
    const float* cW     = (const float*)d_in[9];
    const float* cb     = (const float*)d_in[10];
    const float* inW    = (const float*)d_in[11];
    const float* inb    = (const float*)d_in[12];
    const float* basis0 = (const float*)d_in[13];
    const float* comb0  = (const float*)d_in[14];
    const float* self0  = (const float*)d_in[15];
    const float* basis1 = (const float*)d_in[16];
    const float* comb1  = (const float*)d_in[17];
    const float* self1  = (const float*)d_in[18];
    const float* typeW  = (const float*)d_in[19];
    const float* typeb  = (const float*)d_in[20];

    char* ws = (char*)d_ws;
    size_t off = 0;
    auto alloc = [&](size_t bytes) -> void* {
        void* p = ws + off;
        off = (off + bytes + 255) & ~(size_t)255;
        return p;
    };
    u16* mi1   = (u16*)alloc(256UL * 64 * 512 * 2);
    u16* mi2   = (u16*)alloc(256UL * 64 * 512 * 2);
    u16* x12   = (u16*)alloc(256UL * 64 * 512 * 2);
    u16* x12b  = (u16*)alloc(256UL * 64 * 512 * 2);
    u64* bitsA = (u64*)alloc(256UL * 12 * 64 * 8);
    u64* bitsB = (u64*)alloc(256UL * 12 * 64 * 8);
    u16* wf0   = (u16*)alloc(208UL * 32 * 64 * 8 * 2);
    u16* wf1   = (u16*)alloc(208UL * 32 * 64 * 8 * 2);
    float* t2  = (float*)alloc(512UL * 512 * 4);

    k_wstack2<<<832, 256, 0, stream>>>(basis0, comb0, self0, wf0);
    k_wstack2<<<832, 256, 0, stream>>>(basis1, comb1, self1, wf1);
    k_adjbits<<<3072, 256, 0, stream>>>(adjm, bitsA, bitsB);
    k_prep<<<256, 256, 0, stream>>>(player, pAx, pAy, pBx, pBy, emb, cW, cb, inW, inb, mi1, mi2);
    k_cast<<<3840, 256, 0, stream>>>(enc, mi1, mi2);

    // rgcn pass 1
    k_fused<<<2048, 256, 0, stream>>>(mi1, bitsA, wf0, 0, x12, nullptr);
    k_fused<<<2048, 256, 0, stream>>>(x12, bitsA, wf1, 1, mi2, nullptr);
    // rgcn pass 2
    k_fused<<<2048, 256, 0, stream>>>(mi2, bitsB, wf0, 0, x12b, nullptr);
    k_fused<<<2048, 256, 0, stream>>>(x12b, bitsB, wf1, 2, nullptr, t2);

    k_final<<<256, 64, 0, stream>>>(t2, typeW, typeb, (float*)d_out);
}

// Round 10
// 887.897 us; speedup vs baseline: 1.9755x; 1.9755x over previous
//
#include <hip/hip_runtime.h>
#include <hip/hip_bf16.h>

typedef unsigned short u16;
typedef unsigned long long u64;
typedef __attribute__((ext_vector_type(4))) short short4v;
typedef __attribute__((ext_vector_type(8))) short short8;
typedef __attribute__((ext_vector_type(4))) float floatx4;

__device__ __forceinline__ u16 f2bf(float f) {
    union { float f; unsigned u; } v; v.f = f;
    unsigned r = v.u + 0x7FFF + ((v.u >> 16) & 1);
    return (u16)(r >> 16);
}

// ---------------------------------------------------------------------------
// Wstack fragment builder (validated rounds 1-9).
// element (k,n) at: (k>>5)*16384 + (n>>4)*512 + ((k>>3)&3)*128 + (n&15)*8 + (k&7)
__global__ void k_wstack2(const float* __restrict__ basis, const float* __restrict__ comb,
                          const float* __restrict__ selfW, u16* __restrict__ wf) {
    int bi = blockIdx.x, t = threadIdx.x;
    int kr = t >> 7;             // 0..1
    int nb = (t & 127) * 4;      // n base
    for (int it = 0; it < 4; ++it) {
        int k = bi * 8 + it * 2 + kr;
        float v0, v1, v2, v3;
        if (k < 6144) {
            int r = k >> 9, h = k & 511;
            v0 = v1 = v2 = v3 = 0.f;
            for (int q = 0; q < 6; ++q) {
                float c = comb[r * 6 + q];
                const float4 bz = *(const float4*)(basis + ((size_t)(q * 512 + h)) * 512 + nb);
                v0 += c * bz.x; v1 += c * bz.y; v2 += c * bz.z; v3 += c * bz.w;
            }
        } else {
            int kk = k - 6144;
            v0 = selfW[(size_t)(nb + 0) * 512 + kk];
            v1 = selfW[(size_t)(nb + 1) * 512 + kk];
            v2 = selfW[(size_t)(nb + 2) * 512 + kk];
            v3 = selfW[(size_t)(nb + 3) * 512 + kk];
        }
        float vv[4] = {v0, v1, v2, v3};
        for (int i = 0; i < 4; ++i) {
            int n = nb + i;
            wf[(size_t)(k >> 5) * 16384 + (n >> 4) * 512 + ((k >> 3) & 3) * 128 + (n & 15) * 8 + (k & 7)] = f2bf(vv[i]);
        }
    }
}

// ---------------------------------------------------------------------------
// Bit-packed adjacency (validated round 6): bA/bB[b][12][64] u64 masks.
__global__ void k_adjbits(const int* __restrict__ A, u64* __restrict__ bA, u64* __restrict__ bB) {
    int bi = blockIdx.x;          // b*12 + r
    int b = bi / 12, r = bi % 12;
    const int* Ab = A + (size_t)(b * 13 + (r + 1)) * 62 * 62;
    __shared__ int tile[62 * 62];
    for (int i = threadIdx.x; i < 3844; i += 256) tile[i] = Ab[i];
    __syncthreads();
    int n = threadIdx.x;
    if (n < 64) {
        u64 mA = 0, mB = 0;
        if (n < 62)
            for (int m = 0; m < 62; ++m)
                if (tile[n * 62 + m]) mA |= 1ull << m;
        if (n < 63) {
            int oi = (n == 62) ? 63 : n;
            for (int m = 0; m < 63; ++m) {
                int oj = (m == 62) ? 63 : m;
                int val = (oi < 62 && oj < 62) ? (tile[oi * 62 + oj] ? 1 : 0) : 0;
                int lo = (oi < oj) ? oi : oj, hi = (oi < oj) ? oj : oi;
                if (hi == lo + 2) {
                    int p = (lo >> 1) & 1;
                    int chp = ((lo & 1) == 0) ? (p ? 12 : 11) : (p ? 11 : 12);
                    if (r + 1 == chp) val = 1;
                }
                if (val) mB |= 1ull << m;
            }
        }
        bA[(size_t)bi * 64 + n] = mA;
        bB[(size_t)bi * 64 + n] = mB;
    }
}

// ---------------------------------------------------------------------------
// initial embedding -> mi1 rows 60..63 ; mi2 rows 62,63
__global__ void k_prep(const int* __restrict__ player,
                       const float* __restrict__ pAx, const float* __restrict__ pAy,
                       const float* __restrict__ pBx, const float* __restrict__ pBy,
                       const float* __restrict__ emb, const float* __restrict__ cW,
                       const float* __restrict__ cb, const float* __restrict__ inW,
                       const float* __restrict__ inb,
                       u16* __restrict__ mi1, u16* __restrict__ mi2) {
    int b = blockIdx.x, t = threadIdx.x;
    __shared__ float feat[2][64];
    if (t < 64) {
        int j = t >> 5, d = t & 31;
        float X = j ? pBx[b] : pAx[b];
        float Y = j ? pBy[b] : pAy[b];
        feat[j][d] = fmaxf(cW[d * 2] * X + cW[d * 2 + 1] * Y + cb[d], 0.f);
        feat[j][32 + d] = emb[player[b * 2 + j] * 32 + d];
    }
    __syncthreads();
    for (int h = t; h < 512; h += 256) {
        float a0 = inb[h], a1 = inb[h];
        const float* wrow = inW + h * 64;
        #pragma unroll
        for (int d = 0; d < 64; ++d) {
            float wv = wrow[d];
            a0 += wv * feat[0][d];
            a1 += wv * feat[1][d];
        }
        u16 v0 = f2bf(a0), v1 = f2bf(a1);
        size_t base = (size_t)b * 64 * 512;
        mi1[base + 60 * 512 + h] = v0;
        mi1[base + 61 * 512 + h] = v1;
        mi1[base + 62 * 512 + h] = 0;
        mi1[base + 63 * 512 + h] = 0;
        mi2[base + 62 * 512 + h] = v1;
        mi2[base + 63 * 512 + h] = 0;
    }
}

// enc f32 -> mi1 rows 0..59 ; mi2 rows 0..57
__global__ void k_cast(const float* __restrict__ enc, u16* __restrict__ mi1, u16* __restrict__ mi2) {
    long long e = ((long long)blockIdx.x * 256 + threadIdx.x) * 8;
    if (e >= 256LL * 60 * 512) return;
    int b = (int)(e / (60 * 512));
    int rm = (int)(e % (60 * 512));
    int n = rm / 512, h = rm % 512;
    for (int i = 0; i < 8; ++i) {
        u16 v = f2bf(enc[e + i]);
        mi1[((size_t)b * 64 + n) * 512 + h + i] = v;
        if (n < 58) mi2[((size_t)b * 64 + n) * 512 + h + i] = v;
    }
}

// ---------------------------------------------------------------------------
// Fused RGCN layer, v7 = round-7 v4 structure + cross-iteration W prefetch
// (8 frags of r+1 issued before agg of r) + mode-specialized agg.
// Block = (1 batch, 64-col tile ct), 256 thr = 4 waves; wave w = K-quarter.
__global__ __launch_bounds__(256, 2)
void k_fused(const u16* __restrict__ x, const u64* __restrict__ bits,
             const u16* __restrict__ wf, int mode,
             u16* __restrict__ o16, float* __restrict__ o32) {
    int ct = blockIdx.x & 7, b = blockIdx.x >> 3;
    int t = threadIdx.x, lane = t & 63, w = t >> 6;
    int l15 = lane & 15, lq = lane >> 4;

    __shared__ __align__(16) u16 zs[64 * 264];   // [col][m' 0..255]

    // x fragments: all 64 rows, K-quarter w (one-time load)
    short8 xf[16];
    {
        const u16* xw = x + (size_t)b * 64 * 512 + w * 128 + lq * 8;
        #pragma unroll
        for (int mt = 0; mt < 4; ++mt)
            #pragma unroll
            for (int ks = 0; ks < 4; ++ks)
                xf[mt * 4 + ks] = *(const short8*)(xw + (mt * 16 + l15) * 512 + ks * 32);
    }

    const u16* wbase = wf + (size_t)(ct * 4) * 512 + (size_t)lane * 8;
    const u64* bitb = bits + (size_t)b * 12 * 64;

    floatx4 ay[4];
    #pragma unroll
    for (int i = 0; i < 4; ++i) ay[i] = (floatx4)(0.f);

    // prefetch r=0, ks=0/1 W fragments
    short8 wp[8];
    {
        const u16* wr0 = wbase + (size_t)(w * 4) * 16384;
        #pragma unroll
        for (int i = 0; i < 4; ++i) {
            wp[i]     = *(const short8*)(wr0 + (size_t)i * 512);
            wp[4 + i] = *(const short8*)(wr0 + 16384 + (size_t)i * 512);
        }
    }

    for (int r = 0; r < 13; ++r) {
        // adj masks (row = i*16+l15); self term = identity
        u64 mk[4];
        if (mode == 0) {
            if (r < 12) {
                #pragma unroll
                for (int i = 0; i < 4; ++i) mk[i] = bitb[r * 64 + i * 16 + l15];
            } else {
                #pragma unroll
                for (int i = 0; i < 4; ++i) mk[i] = 1ull << (i * 16 + l15);
            }
        } else {
            mk[3] = (r < 12) ? bitb[r * 64 + 48 + l15] : (1ull << (48 + l15));
        }

        // ---- Z-phase: az = x_q @ W[r, quarter w]
        const u16* wr = wbase + (size_t)(r * 16 + w * 4) * 16384;
        floatx4 az[16];
        #pragma unroll
        for (int i = 0; i < 16; ++i) az[i] = (floatx4)(0.f);
        short8 wv[4], wn_[4];
        // issue ks=2 loads, then MFMA ks=0 from prefetched wp
        #pragma unroll
        for (int i = 0; i < 4; ++i) wv[i] = *(const short8*)(wr + 2 * 16384 + (size_t)i * 512);
        #pragma unroll
        for (int mt = 0; mt < 4; ++mt)
            #pragma unroll
            for (int i = 0; i < 4; ++i)
                az[mt * 4 + i] = __builtin_amdgcn_mfma_f32_16x16x32_bf16(xf[mt * 4 + 0], wp[i], az[mt * 4 + i], 0, 0, 0);
        // issue ks=3 loads, then MFMA ks=1 from prefetched wp
        #pragma unroll
        for (int i = 0; i < 4; ++i) wn_[i] = *(const short8*)(wr + 3 * 16384 + (size_t)i * 512);
        #pragma unroll
        for (int mt = 0; mt < 4; ++mt)
            #pragma unroll
            for (int i = 0; i < 4; ++i)
                az[mt * 4 + i] = __builtin_amdgcn_mfma_f32_16x16x32_bf16(xf[mt * 4 + 1], wp[4 + i], az[mt * 4 + i], 0, 0, 0);
        // ks=2, ks=3
        #pragma unroll
        for (int mt = 0; mt < 4; ++mt)
            #pragma unroll
            for (int i = 0; i < 4; ++i)
                az[mt * 4 + i] = __builtin_amdgcn_mfma_f32_16x16x32_bf16(xf[mt * 4 + 2], wv[i], az[mt * 4 + i], 0, 0, 0);
        #pragma unroll
        for (int mt = 0; mt < 4; ++mt)
            #pragma unroll
            for (int i = 0; i < 4; ++i)
                az[mt * 4 + i] = __builtin_amdgcn_mfma_f32_16x16x32_bf16(xf[mt * 4 + 3], wn_[i], az[mt * 4 + i], 0, 0, 0);

        __syncthreads();   // prior agg's zs reads complete

        // ---- write Z-partials: zs[col][w*64 + row]
        #pragma unroll
        for (int mt = 0; mt < 4; ++mt)
            #pragma unroll
            for (int i = 0; i < 4; ++i) {
                short4v pk;
                #pragma unroll
                for (int rr = 0; rr < 4; ++rr) pk[rr] = (short)f2bf(az[mt * 4 + i][rr]);
                *(short4v*)&zs[(i * 16 + l15) * 264 + w * 64 + mt * 16 + lq * 4] = pk;
            }

        // ---- prefetch r+1 ks=0/1 W frags: in flight across the agg phase
        if (r < 12) {
            const u16* wrn = wbase + (size_t)((r + 1) * 16 + w * 4) * 16384;
            #pragma unroll
            for (int i = 0; i < 4; ++i) {
                wp[i]     = *(const short8*)(wrn + (size_t)i * 512);
                wp[4 + i] = *(const short8*)(wrn + 16384 + (size_t)i * 512);
            }
        }

        __syncthreads();   // zs visible

        // ---- agg: ay^T += Z^T @ adj^T  (A = zs own col-band, B from bitmasks)
        if (mode == 0) {
            short8 adjf[8];   // [i*2+par]
            #pragma unroll
            for (int i = 0; i < 4; ++i)
                #pragma unroll
                for (int par = 0; par < 2; ++par) {
                    unsigned byte = (unsigned)((mk[i] >> (par * 32 + lq * 8)) & 0xFFu);
                    #pragma unroll
                    for (int j = 0; j < 8; ++j)
                        adjf[i * 2 + par][j] = (short)(((byte >> j) & 1) ? 0x3F80 : 0);
                }
            #pragma unroll
            for (int k2 = 0; k2 < 8; ++k2) {
                short8 af = *(const short8*)&zs[(w * 16 + l15) * 264 + k2 * 32 + lq * 8];
                #pragma unroll
                for (int i = 0; i < 4; ++i)
                    ay[i] = __builtin_amdgcn_mfma_f32_16x16x32_bf16(af, adjf[i * 2 + (k2 & 1)], ay[i], 0, 0, 0);
            }
        } else {
            short8 adjf[2];
            #pragma unroll
            for (int par = 0; par < 2; ++par) {
                unsigned byte = (unsigned)((mk[3] >> (par * 32 + lq * 8)) & 0xFFu);
                #pragma unroll
                for (int j = 0; j < 8; ++j)
                    adjf[par][j] = (short)(((byte >> j) & 1) ? 0x3F80 : 0);
            }
            #pragma unroll
            for (int k2 = 0; k2 < 8; ++k2) {
                short8 af = *(const short8*)&zs[(w * 16 + l15) * 264 + k2 * 32 + lq * 8];
                ay[3] = __builtin_amdgcn_mfma_f32_16x16x32_bf16(af, adjf[k2 & 1], ay[3], 0, 0, 0);
            }
        }
    }

    // ---- epilogue: lane holds y[row = i*16+l15][col = ct*64 + w*16 + lq*4 + rr]
    int colb = ct * 64 + w * 16 + lq * 4;
    #pragma unroll
    for (int i = 0; i < 4; ++i) {
        int row = i * 16 + l15;
        if (mode == 0) {
            short4v pk;
            #pragma unroll
            for (int rr = 0; rr < 4; ++rr) pk[rr] = (short)f2bf(fmaxf(ay[i][rr], 0.f));
            *(short4v*)(o16 + ((size_t)b * 64 + row) * 512 + colb) = pk;
        } else if (mode == 1) {
            if (i == 3 && row >= 58 && row <= 61) {
                short4v pk;
                #pragma unroll
                for (int rr = 0; rr < 4; ++rr)
                    pk[rr] = (short)f2bf(1.f / (1.f + __expf(-ay[3][rr])));
                *(short4v*)(o16 + ((size_t)b * 64 + row) * 512 + colb) = pk;
            }
        } else {
            if (i == 3 && (row == 60 || row == 62)) {
                float4 pv;
                pv.x = 1.f / (1.f + __expf(-ay[3][0]));
                pv.y = 1.f / (1.f + __expf(-ay[3][1]));
                pv.z = 1.f / (1.f + __expf(-ay[3][2]));
                pv.w = 1.f / (1.f + __expf(-ay[3][3]));
                int slot = (row == 60) ? (b * 2) : (b * 2 + 1);
                *(float4*)(o32 + (size_t)slot * 512 + colb) = pv;
            }
        }
    }
}

// logits = [black|white] @ type_W^T + type_b
__global__ void k_final(const float* __restrict__ t2, const float* __restrict__ tW,
                        const float* __restrict__ tb, float* __restrict__ outp) {
    int b = blockIdx.x, l = threadIdx.x;   // 64 threads
    float a[11];
    #pragma unroll
    for (int j = 0; j < 11; ++j) a[j] = 0.f;
    for (int it = 0; it < 16; ++it) {
        int h = it * 64 + l;
        float c = (h < 512) ? t2[(b * 2 + 1) * 512 + h] : t2[(b * 2 + 0) * 512 + (h - 512)];
        #pragma unroll
        for (int j = 0; j < 11; ++j) a[j] += c * tW[j * 1024 + h];
    }
    #pragma unroll
    for (int j = 0; j < 11; ++j) {
        float v = a[j];
        for (int off = 32; off > 0; off >>= 1) v += __shfl_down(v, off, 64);
        if (l == 0) outp[b * 11 + j] = v + tb[j];
    }
}

// ---------------------------------------------------------------------------
extern "C" void kernel_launch(void* const* d_in, const int* in_sizes, int n_in,
                              void* d_out, int out_size, void* d_ws, size_t ws_size,
                              hipStream_t stream) {
    const int*   player = (const int*)d_in[0];
    const float* enc    = (const float*)d_in[2];
    const int*   adjm   = (const int*)d_in[3];
    const float* pAx    = (const float*)d_in[4];
    const float* pAy    = (const float*)d_in[5];
    const float* pBx    = (const float*)d_in[6];
    const float* pBy    = (const float*)d_in[7];
    const float* emb    = (const float*)d_in[8];
    const float* cW     = (const float*)d_in[9];
    const float* cb     = (const float*)d_in[10];
    const float* inW    = (const float*)d_in[11];
    const float* inb    = (const float*)d_in[12];
    const float* basis0 = (const float*)d_in[13];
    const float* comb0  = (const float*)d_in[14];
    const float* self0  = (const float*)d_in[15];
    const float* basis1 = (const float*)d_in[16];
    const float* comb1  = (const float*)d_in[17];
    const float* self1  = (const float*)d_in[18];
    const float* typeW  = (const float*)d_in[19];
    const float* typeb  = (const float*)d_in[20];

    char* ws = (char*)d_ws;
    size_t off = 0;
    auto alloc = [&](size_t bytes) -> void* {
        void* p = ws + off;
        off = (off + bytes + 255) & ~(size_t)255;
        return p;
    };
    u16* mi1   = (u16*)alloc(256UL * 64 * 512 * 2);
    u16* mi2   = (u16*)alloc(256UL * 64 * 512 * 2);
    u16* x12   = (u16*)alloc(256UL * 64 * 512 * 2);
    u16* x12b  = (u16*)alloc(256UL * 64 * 512 * 2);
    u64* bitsA = (u64*)alloc(256UL * 12 * 64 * 8);
    u64* bitsB = (u64*)alloc(256UL * 12 * 64 * 8);
    u16* wf0   = (u16*)alloc(208UL * 32 * 64 * 8 * 2);
    u16* wf1   = (u16*)alloc(208UL * 32 * 64 * 8 * 2);
    float* t2  = (float*)alloc(512UL * 512 * 4);

    k_wstack2<<<832, 256, 0, stream>>>(basis0, comb0, self0, wf0);
    k_wstack2<<<832, 256, 0, stream>>>(basis1, comb1, self1, wf1);
    k_adjbits<<<3072, 256, 0, stream>>>(adjm, bitsA, bitsB);
    k_prep<<<256, 256, 0, stream>>>(player, pAx, pAy, pBx, pBy, emb, cW, cb, inW, inb, mi1, mi2);
    k_cast<<<3840, 256, 0, stream>>>(enc, mi1, mi2);

    // rgcn pass 1
    k_fused<<<2048, 256, 0, stream>>>(mi1, bitsA, wf0, 0, x12, nullptr);
    k_fused<<<2048, 256, 0, stream>>>(x12, bitsA, wf1, 1, mi2, nullptr);
    // rgcn pass 2
    k_fused<<<2048, 256, 0, stream>>>(mi2, bitsB, wf0, 0, x12b, nullptr);
    k_fused<<<2048, 256, 0, stream>>>(x12b, bitsB, wf1, 2, nullptr, t2);

    k_final<<<256, 64, 0, stream>>>(t2, typeW, typeb, (float*)d_out);
}